// Round 1
// baseline (328.338 us; speedup 1.0000x reference)
//
#include <hip/hip_runtime.h>
#include <hip/hip_bf16.h>

// FlexibleGCN forward on MI355X — Round 9:
//  * FC head fused into agg2: each agg2 block (4 nodes) stages its 4x64
//    embedding in 1KB LDS and computes logits in-block (64 MACs/thread,
//    Wfc L1-resident). Removes fc_kernel dispatch + 25.6MB emb re-read.
//  * Rest identical to Round 8 (2 edges/wave depth-8 agg, bf16 hp & h1,
//    packed CSR staging).

constexpr int IN_DIM  = 128;
constexpr int HDIM    = 64;
constexpr int NBLK_A  = 256;   // blocks in pass A (must match histg stride)
constexpr int BSH     = 8;     // bucket shift: 256 nodes per bucket
constexpr int MAXNB   = 512;   // max buckets supported (N <= 131072)

__device__ __forceinline__ float bf2f(unsigned int u) {
    return __uint_as_float(u << 16);
}
__device__ __forceinline__ unsigned short f2bf_bits(float f) {
    __hip_bfloat16 b = __float2bfloat16(f);
    return *(unsigned short*)&b;
}

// ---------- CSR build ----------

__global__ void binA_count(const int* __restrict__ dst, int* __restrict__ histg,
                           int E, int NB, int chunk) {
    __shared__ int h[MAXNB];
    for (int i = threadIdx.x; i < NB; i += 256) h[i] = 0;
    __syncthreads();
    int beg = blockIdx.x * chunk;
    int end = min(E, beg + chunk);
    for (int e = beg + threadIdx.x; e < end; e += 256)
        atomicAdd(&h[dst[e] >> BSH], 1);
    __syncthreads();
    for (int i = threadIdx.x; i < NB; i += 256)
        histg[i * NBLK_A + blockIdx.x] = h[i];
}

__global__ void binA_scanblocks(int* __restrict__ histg, int* __restrict__ btot) {
    __shared__ int sm[NBLK_A];
    int tid = threadIdx.x;
    int v = histg[blockIdx.x * NBLK_A + tid];
    sm[tid] = v;
    __syncthreads();
    for (int off = 1; off < NBLK_A; off <<= 1) {
        int t = (tid >= off) ? sm[tid - off] : 0;
        __syncthreads();
        sm[tid] += t;
        __syncthreads();
    }
    histg[blockIdx.x * NBLK_A + tid] = sm[tid] - v;   // exclusive
    if (tid == NBLK_A - 1) btot[blockIdx.x] = sm[tid];
}

__global__ void binA_scanbuckets(const int* __restrict__ btot, int* __restrict__ bucketbase,
                                 int NB) {
    __shared__ int sm[MAXNB];
    int tid = threadIdx.x;    // blockDim = MAXNB
    int v = (tid < NB) ? btot[tid] : 0;
    sm[tid] = v;
    __syncthreads();
    for (int off = 1; off < MAXNB; off <<= 1) {
        int t = (tid >= off) ? sm[tid - off] : 0;
        __syncthreads();
        sm[tid] += t;
        __syncthreads();
    }
    if (tid < NB) bucketbase[tid] = sm[tid] - v;
    if (tid == MAXNB - 1) bucketbase[NB] = sm[tid];   // == E
}

__global__ void binA_scatter(const int* __restrict__ src, const int* __restrict__ dst,
                             const int* __restrict__ histg, const int* __restrict__ bucketbase,
                             int* __restrict__ staging, int E, int NB, int chunk) {
    __shared__ int cur[MAXNB];
    for (int i = threadIdx.x; i < NB; i += 256)
        cur[i] = bucketbase[i] + histg[i * NBLK_A + blockIdx.x];
    __syncthreads();
    int beg = blockIdx.x * chunk;
    int end = min(E, beg + chunk);
    for (int e = beg + threadIdx.x; e < end; e += 256) {
        int s = src[e];
        int d = dst[e];
        int pos = atomicAdd(&cur[d >> BSH], 1);
        staging[pos] = (s << BSH) | (d & 255);    // src<2^17, local dst 8 bits
    }
}

__global__ void binB_finalize(const int* __restrict__ staging, const int* __restrict__ bucketbase,
                              int* __restrict__ rowptr, int* __restrict__ esrc,
                              float* __restrict__ dinv, int N, int NB) {
    __shared__ int cnt[256], sm[256], cur[256];
    int tid = threadIdx.x;
    int b = blockIdx.x;
    int node0 = b << BSH;
    int nloc = min(256, N - node0);
    int ebeg = bucketbase[b], eend = bucketbase[b + 1];
    cnt[tid] = 0;
    __syncthreads();
    for (int e = ebeg + tid; e < eend; e += 256)
        atomicAdd(&cnt[staging[e] & 255], 1);
    __syncthreads();
    int v = cnt[tid];
    sm[tid] = v;
    __syncthreads();
    for (int off = 1; off < 256; off <<= 1) {
        int t = (tid >= off) ? sm[tid - off] : 0;
        __syncthreads();
        sm[tid] += t;
        __syncthreads();
    }
    int excl = sm[tid] - v;
    cur[tid] = excl;
    __syncthreads();
    if (tid < nloc) {
        rowptr[node0 + tid] = ebeg + excl;
        dinv[node0 + tid] = rsqrtf((float)v + 1.0f);   // +1 self-loop
    }
    if (b == 0 && tid == 0) rowptr[N] = bucketbase[NB];
    for (int e = ebeg + tid; e < eend; e += 256) {
        int p = staging[e];
        int pos = ebeg + atomicAdd(&cur[p & 255], 1);
        esrc[pos] = p >> BSH;
    }
}

// ---------- dense layers ----------

// Y[n][64] = X[n][K] @ W[K][64]; optional *dinv[row], optional +bias.
// 256 threads, tile 128 rows x 64 cols; thread = 8x4 micro-tile; KC=32.
template<int K, bool IBF16, bool SCALE, bool BIAS, bool OBF16>
__device__ __forceinline__ void gemm_body(
        const void* __restrict__ Xv, const float* __restrict__ W,
        const float* __restrict__ bias, const float* __restrict__ dinv,
        void* __restrict__ Yv, int n) {
    constexpr int KC = 32;
    constexpr int XSTR = 132;                 // floats
    __shared__ float Xt[KC * XSTR];           // 16.9 KB
    __shared__ float Ws[KC * 64];             // 8 KB
    const int tid = threadIdx.x;
    const int node0 = blockIdx.x * 128;
    const int r0 = (tid >> 4) * 8;            // 0..120
    const int c0 = (tid & 15) * 4;            // 0..60

    float acc[8][4];
#pragma unroll
    for (int a = 0; a < 8; ++a)
#pragma unroll
        for (int b = 0; b < 4; ++b) acc[a][b] = 0.f;

    for (int kc = 0; kc < K; kc += KC) {
        __syncthreads();
#pragma unroll
        for (int i = 0; i < 4; ++i) {
            int s = tid + i * 256;
            int row = s >> 3;
            int kq = s & 7;
            int grow = node0 + row;
            float4 v = make_float4(0.f, 0.f, 0.f, 0.f);
            if (grow < n) {
                if (IBF16) {
                    uint2 u = *(const uint2*)&((const unsigned short*)Xv)[(size_t)grow * K + kc + kq * 4];
                    v.x = bf2f(u.x & 0xffff); v.y = bf2f(u.x >> 16);
                    v.z = bf2f(u.y & 0xffff); v.w = bf2f(u.y >> 16);
                } else {
                    v = *(const float4*)&((const float*)Xv)[(size_t)grow * K + kc + kq * 4];
                }
            }
            Xt[(kq * 4 + 0) * XSTR + row] = v.x;
            Xt[(kq * 4 + 1) * XSTR + row] = v.y;
            Xt[(kq * 4 + 2) * XSTR + row] = v.z;
            Xt[(kq * 4 + 3) * XSTR + row] = v.w;
        }
#pragma unroll
        for (int i = 0; i < 2; ++i) {
            int s = tid + i * 256;
            *(float4*)&Ws[s * 4] = *(const float4*)&W[(size_t)kc * 64 + s * 4];
        }
        __syncthreads();
#pragma unroll
        for (int kk = 0; kk < KC; kk += 4) {
            float4 xa[4][2];
            float4 wv[4];
#pragma unroll
            for (int i = 0; i < 4; ++i) {
                xa[i][0] = *(const float4*)&Xt[(kk + i) * XSTR + r0];
                xa[i][1] = *(const float4*)&Xt[(kk + i) * XSTR + r0 + 4];
                wv[i]    = *(const float4*)&Ws[(kk + i) * 64 + c0];
            }
#pragma unroll
            for (int i = 0; i < 4; ++i) {
                const float* xp = (const float*)&xa[i][0];
                const float* wp = (const float*)&wv[i];
#pragma unroll
                for (int rr = 0; rr < 8; ++rr)
#pragma unroll
                    for (int cc = 0; cc < 4; ++cc)
                        acc[rr][cc] += xp[rr] * wp[cc];
            }
        }
    }
#pragma unroll
    for (int rr = 0; rr < 8; ++rr) {
        int node = node0 + r0 + rr;
        if (node < n) {
            float d = SCALE ? dinv[node] : 1.0f;
            float t[4];
#pragma unroll
            for (int cc = 0; cc < 4; ++cc) {
                float v = acc[rr][cc];
                if (BIAS) v += bias[c0 + cc];
                t[cc] = v * d;
            }
            if (OBF16) {
                __hip_bfloat16 vb[4];
#pragma unroll
                for (int cc = 0; cc < 4; ++cc) vb[cc] = __float2bfloat16(t[cc]);
                *(uint2*)&((__hip_bfloat16*)Yv)[(size_t)node * 64 + c0] = *(uint2*)vb;
            } else {
                *(float4*)&((float*)Yv)[(size_t)node * 64 + c0] = *(float4*)t;
            }
        }
    }
}

__global__ __launch_bounds__(256, 4) void gemm1_kernel(
        const float* X, const float* W, const float* dinv, void* Y, int n) {
    gemm_body<IN_DIM, false, true, false, true>(X, W, nullptr, dinv, Y, n);
}
__global__ __launch_bounds__(256, 4) void gemm2_kernel(
        const void* X, const float* W, const float* dinv, void* Y, int n) {
    gemm_body<HDIM, true, true, false, true>(X, W, nullptr, dinv, Y, n);
}

// One wave per node, 2 edges per wave: half-wave h (32 lanes) takes edges
// k+2i+h; lane l holds packed features {2l, 2l+1} as one uint (2 bf16).
// Depth-8 batches -> 16 edges in flight. Cross-half shfl_xor(32) combine.
template<bool OBF16>
__device__ __forceinline__ void agg_body(
        const unsigned short* __restrict__ hp, const int* __restrict__ esrc,
        const int* __restrict__ rowptr, const float* __restrict__ dinv,
        const float* __restrict__ bias, void* __restrict__ out, int n) {
    int node = blockIdx.x * 4 + (threadIdx.x >> 6);
    if (node >= n) return;
    int lane = threadIdx.x & 63;
    int half = lane >> 5;
    int l = lane & 31;
    const unsigned int* hp32 = (const unsigned int*)hp;   // row s -> hp32[s*32 + l]
    int beg = rowptr[node], end = rowptr[node + 1];

    float ax = 0.f, ay = 0.f;
    {   // self-loop, counted by half 0 only
        unsigned int u = hp32[(size_t)node * 32 + l];
        if (half == 0) { ax = bf2f(u & 0xffff); ay = bf2f(u >> 16); }
    }
    int k = beg;
    for (; k + 16 <= end; k += 16) {
        int s[8];
#pragma unroll
        for (int i = 0; i < 8; ++i) s[i] = esrc[k + 2 * i + half];
        unsigned int u[8];
#pragma unroll
        for (int i = 0; i < 8; ++i) u[i] = hp32[(size_t)s[i] * 32 + l];
        float vx[8], vy[8];
#pragma unroll
        for (int i = 0; i < 8; ++i) { vx[i] = bf2f(u[i] & 0xffff); vy[i] = bf2f(u[i] >> 16); }
        ax += ((vx[0] + vx[1]) + (vx[2] + vx[3])) + ((vx[4] + vx[5]) + (vx[6] + vx[7]));
        ay += ((vy[0] + vy[1]) + (vy[2] + vy[3])) + ((vy[4] + vy[5]) + (vy[6] + vy[7]));
    }
    if (k < end) {  // 1..15 remaining: one predicated depth-8 batch (16 slots)
        int s[8];
#pragma unroll
        for (int i = 0; i < 8; ++i) s[i] = esrc[min(k + 2 * i + half, end - 1)];
        unsigned int u[8];
#pragma unroll
        for (int i = 0; i < 8; ++i) u[i] = hp32[(size_t)s[i] * 32 + l];
        float tx = 0.f, ty = 0.f;
#pragma unroll
        for (int i = 0; i < 8; ++i) {
            bool m = (k + 2 * i + half) < end;
            tx += m ? bf2f(u[i] & 0xffff) : 0.f;
            ty += m ? bf2f(u[i] >> 16)    : 0.f;
        }
        ax += tx; ay += ty;
    }
    // combine halves (both halves end with the full sum)
    ax += __shfl_xor(ax, 32, 64);
    ay += __shfl_xor(ay, 32, 64);

    if (half == 0) {
        float d = dinv[node];
        float ox = fmaxf(d * ax + bias[2 * l], 0.f);
        float oy = fmaxf(d * ay + bias[2 * l + 1], 0.f);
        if (OBF16) {
            unsigned int packed = (unsigned int)f2bf_bits(ox) | ((unsigned int)f2bf_bits(oy) << 16);
            ((unsigned int*)out)[(size_t)node * 32 + l] = packed;
        } else {
            float2 o = make_float2(ox, oy);
            ((float2*)out)[(size_t)node * 32 + l] = o;
        }
    }
}

__global__ __launch_bounds__(256) void agg1_kernel(
        const unsigned short* hp, const int* esrc, const int* rowptr,
        const float* dinv, const float* bias, void* out, int n) {
    agg_body<true>(hp, esrc, rowptr, dinv, bias, out, n);
}

// agg2 with the FC head fused: after the halves combine, half 0 writes the
// ReLU'd embedding to global AND to a 4x64 LDS tile; then the whole block
// computes logits = h @ Wfc + bfc (one output per thread, Wfc L1-resident).
__global__ __launch_bounds__(256) void agg2_fc_kernel(
        const unsigned short* __restrict__ hp, const int* __restrict__ esrc,
        const int* __restrict__ rowptr, const float* __restrict__ dinv,
        const float* __restrict__ bias,              // b2
        const float* __restrict__ Wfc, const float* __restrict__ bfc,
        float* __restrict__ emb, float* __restrict__ logits, int n) {
    __shared__ float hsm[4][64];
    const int w = threadIdx.x >> 6;
    const int node = blockIdx.x * 4 + w;
    const int lane = threadIdx.x & 63;
    const int half = lane >> 5;
    const int l = lane & 31;
    const bool valid = node < n;

    if (valid) {
        const unsigned int* hp32 = (const unsigned int*)hp;
        int beg = rowptr[node], end = rowptr[node + 1];
        float ax = 0.f, ay = 0.f;
        {   // self-loop, counted by half 0 only
            unsigned int u = hp32[(size_t)node * 32 + l];
            if (half == 0) { ax = bf2f(u & 0xffff); ay = bf2f(u >> 16); }
        }
        int k = beg;
        for (; k + 16 <= end; k += 16) {
            int s[8];
#pragma unroll
            for (int i = 0; i < 8; ++i) s[i] = esrc[k + 2 * i + half];
            unsigned int u[8];
#pragma unroll
            for (int i = 0; i < 8; ++i) u[i] = hp32[(size_t)s[i] * 32 + l];
            float vx[8], vy[8];
#pragma unroll
            for (int i = 0; i < 8; ++i) { vx[i] = bf2f(u[i] & 0xffff); vy[i] = bf2f(u[i] >> 16); }
            ax += ((vx[0] + vx[1]) + (vx[2] + vx[3])) + ((vx[4] + vx[5]) + (vx[6] + vx[7]));
            ay += ((vy[0] + vy[1]) + (vy[2] + vy[3])) + ((vy[4] + vy[5]) + (vy[6] + vy[7]));
        }
        if (k < end) {
            int s[8];
#pragma unroll
            for (int i = 0; i < 8; ++i) s[i] = esrc[min(k + 2 * i + half, end - 1)];
            unsigned int u[8];
#pragma unroll
            for (int i = 0; i < 8; ++i) u[i] = hp32[(size_t)s[i] * 32 + l];
            float tx = 0.f, ty = 0.f;
#pragma unroll
            for (int i = 0; i < 8; ++i) {
                bool m = (k + 2 * i + half) < end;
                tx += m ? bf2f(u[i] & 0xffff) : 0.f;
                ty += m ? bf2f(u[i] >> 16)    : 0.f;
            }
            ax += tx; ay += ty;
        }
        ax += __shfl_xor(ax, 32, 64);
        ay += __shfl_xor(ay, 32, 64);

        if (half == 0) {
            float d = dinv[node];
            float ox = fmaxf(d * ax + bias[2 * l], 0.f);
            float oy = fmaxf(d * ay + bias[2 * l + 1], 0.f);
            ((float2*)emb)[(size_t)node * 32 + l] = make_float2(ox, oy);
            *(float2*)&hsm[w][2 * l] = make_float2(ox, oy);
        }
    } else if (half == 0) {
        *(float2*)&hsm[w][2 * l] = make_float2(0.f, 0.f);
    }
    __syncthreads();

    // FC: thread -> (node w, output o = lane). 64 MACs; Wfc row reads are
    // coalesced (256B/wave) and L1-resident (16KB working set).
    const int o = lane;
    float acc = bfc[o];
    const float* hrow = hsm[w];
#pragma unroll 16
    for (int f = 0; f < 64; ++f)
        acc += hrow[f] * Wfc[f * 64 + o];
    if (valid) logits[(size_t)node * 64 + o] = acc;
}

extern "C" void kernel_launch(void* const* d_in, const int* in_sizes, int n_in,
                              void* d_out, int out_size, void* d_ws, size_t ws_size,
                              hipStream_t stream) {
    const float* x   = (const float*)d_in[0];
    const float* W1  = (const float*)d_in[1];
    const float* b1  = (const float*)d_in[2];
    const float* W2  = (const float*)d_in[3];
    const float* b2  = (const float*)d_in[4];
    const float* Wfc = (const float*)d_in[5];
    const float* bfc = (const float*)d_in[6];
    const int*  eidx = (const int*)d_in[7];

    const int N = in_sizes[0] / IN_DIM;     // 100000
    const int E = in_sizes[7] / 2;          // 1600000
    const int* src = eidx;
    const int* dst = eidx + E;

    const int NB    = (N + 255) >> BSH;     // 391 buckets
    const int chunk = (E + NBLK_A - 1) / NBLK_A;

    // ws layout (4B units): rowptr[N+2] | dinv[N] | histg[NB*NBLK_A] | btot[512]
    //   | bucketbase[512] | esrc[E] | bufA[N*64 floats] | bufB[N*64 floats]
    // staging int[E] and hp (bf16) alias bufA; h1 (bf16) aliases bufB.
    int*   rowptr     = (int*)d_ws;
    float* dinv       = (float*)(rowptr + (N + 2));
    int*   histg      = (int*)(dinv + N);
    int*   btot       = histg + (size_t)NB * NBLK_A + (((size_t)NB * NBLK_A) & 1);
    int*   bucketbase = btot + 512;
    int*   esrc       = bucketbase + 512;
    float* bufA       = (float*)(esrc + E + (E & 1));
    float* bufB       = bufA + (size_t)N * HDIM;
    int*   staging    = (int*)bufA;
    unsigned short* hp = (unsigned short*)bufA;   // bf16 bits
    unsigned short* h1 = (unsigned short*)bufB;   // bf16 bits

    float* emb    = (float*)d_out;
    float* logits = emb + (size_t)N * HDIM;

    // ---- CSR build (shared by both conv layers) ----
    binA_count<<<NBLK_A, 256, 0, stream>>>(dst, histg, E, NB, chunk);
    binA_scanblocks<<<NB, NBLK_A, 0, stream>>>(histg, btot);
    binA_scanbuckets<<<1, MAXNB, 0, stream>>>(btot, bucketbase, NB);
    binA_scatter<<<NBLK_A, 256, 0, stream>>>(src, dst, histg, bucketbase, staging, E, NB, chunk);
    binB_finalize<<<NB, 256, 0, stream>>>(staging, bucketbase, rowptr, esrc, dinv, N, NB);

    const int gBlocks = (N + 127) / 128;
    const int aBlocks = (N + 3) / 4;

    // ---- layer 1 ----  hp1 (bf16) aliases staging: staging dead after binB.
    gemm1_kernel<<<gBlocks, 256, 0, stream>>>(x, W1, dinv, hp, N);
    agg1_kernel<<<aBlocks, 256, 0, stream>>>(hp, esrc, rowptr, dinv, b1, h1, N);

    // ---- layer 2 ----
    gemm2_kernel<<<gBlocks, 256, 0, stream>>>(h1, W2, dinv, hp, N);

    // ---- layer 2 agg + FC head (fused) ----
    agg2_fc_kernel<<<aBlocks, 256, 0, stream>>>(hp, esrc, rowptr, dinv, b2,
                                                Wfc, bfc, emb, logits, N);
}